// Round 13
// baseline (415.425 us; speedup 1.0000x reference)
//
#include <hip/hip_runtime.h>
#include <hip/hip_bf16.h>

#define NODES 13627
#define DIM   500

typedef short short8 __attribute__((ext_vector_type(8)));
typedef float f32x4 __attribute__((ext_vector_type(4)));
typedef float floatx2 __attribute__((ext_vector_type(2)));

__device__ inline float wave_reduce_sum(float v) {
#pragma unroll
    for (int o = 32; o > 0; o >>= 1) v += __shfl_xor(v, o, 64);
    return v;
}

__device__ inline void store_v(float* p, float v) { *p = v; }
__device__ inline void store_v(__hip_bfloat16* p, float v) { *p = __float2bfloat16(v); }

// bf16 (packed pair in uint) -> f32, exact
__device__ inline float blo(unsigned w) { unsigned t = w << 16;        return __builtin_bit_cast(float, t); }
__device__ inline float bhi(unsigned w) { unsigned t = w & 0xffff0000u; return __builtin_bit_cast(float, t); }

// fp8 e4m3 (OCP, HW convert)
__device__ inline unsigned char to_fp8(float v) {
    int r = __builtin_amdgcn_cvt_pk_fp8_f32(v, v, 0, false);
    return (unsigned char)(r & 0xff);
}

// pack two floats into bf16x2 word (RNE)
__device__ inline unsigned pk2bf(float a, float b) {
    unsigned la = (unsigned)__builtin_bit_cast(unsigned short, __float2bfloat16(a));
    unsigned hb = (unsigned)__builtin_bit_cast(unsigned short, __float2bfloat16(b));
    return la | (hb << 16);
}

struct b4 { __hip_bfloat16 a, b, c, d; };

// ---------------------------------------------------------------------------
// CSR build: histogram -> scan -> scatter
// ---------------------------------------------------------------------------
__global__ __launch_bounds__(256) void hist_kernel(const int* __restrict__ dst,
                                                   int* __restrict__ cnt, int E) {
    int i = blockIdx.x * blockDim.x + threadIdx.x;
    if (i < E) atomicAdd(&cnt[dst[i]], 1);
}

__global__ __launch_bounds__(1024) void scan_kernel(int* __restrict__ cnt_cur,
                                                    int* __restrict__ off, int n) {
    __shared__ int wsum[16];
    const int tid = threadIdx.x, lane = tid & 63, w = tid >> 6;
    int carry = 0;
    for (int base = 0; base < n; base += 1024) {
        int i = base + tid;
        int v = (i < n) ? cnt_cur[i] : 0;
        int s = v;
#pragma unroll
        for (int o = 1; o < 64; o <<= 1) {
            int t = __shfl_up(s, o, 64);
            if (lane >= o) s += t;
        }
        if (lane == 63) wsum[w] = s;
        __syncthreads();
        if (w == 0 && lane < 16) {
            int x = wsum[lane];
            int sx = x;
#pragma unroll
            for (int o = 1; o < 16; o <<= 1) {
                int t = __shfl_up(sx, o, 64);
                if (lane >= o) sx += t;
            }
            wsum[lane] = sx;
        }
        __syncthreads();
        int wo = (w == 0) ? 0 : wsum[w - 1];
        int total = wsum[15];
        int excl = carry + wo + (s - v);
        if (i < n) { off[i] = excl; cnt_cur[i] = excl; }
        carry += total;
        __syncthreads();
    }
    if (tid == 0) off[n] = carry;
}

__global__ __launch_bounds__(256) void scatter_kernel(const int* __restrict__ src,
                                                      const int* __restrict__ dst,
                                                      int* __restrict__ cur,
                                                      int* __restrict__ ssrc, int E) {
    int i = blockIdx.x * blockDim.x + threadIdx.x;
    if (i < E) {
        int p = atomicAdd(&cur[dst[i]], 1);
        ssrc[p] = src[i];
    }
}

// ---------------------------------------------------------------------------
// Fused conversion / packing (weights + bias + x) in ONE launch.
// ---------------------------------------------------------------------------
__global__ __launch_bounds__(256) void convert_all_kernel(
    const float* __restrict__ x,
    const float* __restrict__ Wl1, const float* __restrict__ Wr1,
    const float* __restrict__ Wl2, const float* __restrict__ Wr2,
    const float* __restrict__ Ws1, const float* __restrict__ Ws2,
    const float* __restrict__ bs1, const float* __restrict__ bs2,
    __hip_bfloat16* __restrict__ W1T, __hip_bfloat16* __restrict__ W2T,
    __hip_bfloat16* __restrict__ WsT, float* __restrict__ bcat,
    __hip_bfloat16* __restrict__ xb, int M) {
    int i = blockIdx.x * 256 + threadIdx.x;
    if (i < 327680) {
        int n = i >> 9, k = i & 511;
        float v = 0.f;
        if (k < 500) {
            if (n < 300) v = Wl1[k * 300 + n];
            else if (n < 600) v = Wr1[k * 300 + n - 300];
        }
        W1T[i] = __float2bfloat16(v);
    } else if (i < 409600) {
        int j = i - 327680;
        int n = j / 320, k = j - n * 320;
        float v = 0.f;
        if (k < 300) {
            if (n < 100) v = Wl2[k * 100 + n];
            else if (n < 200) v = Wr2[k * 100 + n - 100];
        }
        W2T[j] = __float2bfloat16(v);
    } else if (i < 540672) {
        int j = i - 409600;
        int n = j >> 9, k = j & 511;
        float v = 0.f;
        if (k < 500) {
            if (n < 100) v = Ws1[k * 100 + n];
            else if (n < 200) v = Ws2[k * 100 + n - 100];
        }
        WsT[j] = __float2bfloat16(v);
    } else if (i < 540928) {
        int n = i - 540672;
        float v = 0.f;
        if (n < 100) v = bs1[n];
        else if (n < 200) v = bs2[n - 100];
        bcat[n] = v;
    } else {
        int j = i - 540928;
        if (j >= M * 128) return;
        int m = j >> 7, k = (j & 127) << 2;
        b4 o;
        if (k < 500) {
            float4 v = *(const float4*)(x + (size_t)m * 500 + k);
            o.a = __float2bfloat16(v.x); o.b = __float2bfloat16(v.y);
            o.c = __float2bfloat16(v.z); o.d = __float2bfloat16(v.w);
        } else {
            o.a = o.b = o.c = o.d = __float2bfloat16(0.f);
        }
        *(b4*)(xb + (size_t)m * 512 + k) = o;
    }
}

// ---------------------------------------------------------------------------
// bf16 MFMA GEMM: C[M,Nn] = A[M,Kp] @ BT[Nn,Kp]^T   (BM=128, BN=64, BK=32)
// EPI=1 (layer-1 pack) / EPI=2 (layer-2 pack): also computes per-row
//   sxl[gm] += 0.6*att·xl_row, sxr[gm] += 0.6*att·xr_row via quad-shuffle
//   reduce + distinct-address atomicAdd (fused attdot — no extra launches).
// EPI=3: skip epilogue.
// ---------------------------------------------------------------------------
template <int EPI, typename TC>
__global__ __launch_bounds__(256) void mfma_gemm(
    const __hip_bfloat16* __restrict__ A, const __hip_bfloat16* __restrict__ BT,
    TC* __restrict__ C, const float* __restrict__ bias, const float* __restrict__ h2,
    unsigned char* __restrict__ p8, __hip_bfloat16* __restrict__ pb,
    const float* __restrict__ attw, float* __restrict__ sxl, float* __restrict__ sxr,
    int M, int Kp, int Nn, int ldc) {
    __shared__ short AsF[8 * 64 * 8];
    __shared__ short BsF[4 * 64 * 8];
    const int t = threadIdx.x;
    const int w = t >> 6, lane = t & 63;
    const int c = t & 3, rr = t >> 2;
    const int m0 = blockIdx.y * 128, n0 = blockIdx.x * 64;

    f32x4 acc[2][4];
#pragma unroll
    for (int i = 0; i < 2; i++)
#pragma unroll
        for (int j = 0; j < 4; j++) acc[i][j] = (f32x4){0.f, 0.f, 0.f, 0.f};

    for (int k0 = 0; k0 < Kp; k0 += 32) {
#pragma unroll
        for (int r = 0; r < 2; r++) {
            int m = r * 64 + rr;
            int gm = m0 + m; if (gm >= M) gm = M - 1;
            float4 v = *(const float4*)(A + (size_t)gm * Kp + k0 + c * 8);
            int mi = m >> 4, sl = m & 15;
            *(float4*)(&AsF[(mi * 64 + c * 16 + sl) * 8]) = v;
        }
        {
            int n = rr;
            float4 v = *(const float4*)(BT + (size_t)(n0 + n) * Kp + k0 + c * 8);
            int ni = n >> 4, sl = n & 15;
            *(float4*)(&BsF[(ni * 64 + c * 16 + sl) * 8]) = v;
        }
        __syncthreads();
        short8 a0 = *(const short8*)(&AsF[((w * 2 + 0) * 64 + lane) * 8]);
        short8 a1 = *(const short8*)(&AsF[((w * 2 + 1) * 64 + lane) * 8]);
#pragma unroll
        for (int j = 0; j < 4; j++) {
            short8 b = *(const short8*)(&BsF[(j * 64 + lane) * 8]);
            acc[0][j] = __builtin_amdgcn_mfma_f32_16x16x32_bf16(a0, b, acc[0][j], 0, 0, 0);
            acc[1][j] = __builtin_amdgcn_mfma_f32_16x16x32_bf16(a1, b, acc[1][j], 0, 0, 0);
        }
        __syncthreads();
    }

    const int q = lane >> 4, sl = lane & 15;
    if constexpr (EPI == 1 || EPI == 2) {
        constexpr int XL_END = (EPI == 1) ? 300 : 100;
        constexpr int XR_END = 2 * XL_END;
        constexpr int SL8s   = (EPI == 1) ? 304 : 112;
        constexpr int SRBs   = (EPI == 1) ? 320 : 128;
        const bool hasXl = n0 < XL_END;
        const bool hasXr = (n0 + 63 >= XL_END) && (n0 < XR_END);
#pragma unroll
        for (int i = 0; i < 2; i++) {
#pragma unroll
            for (int reg = 0; reg < 4; reg++) {
                int gm = m0 + w * 32 + i * 16 + q * 4 + reg;
                if (gm >= M) continue;       // uniform across the 16-lane sl group
                float axl = 0.f, axr = 0.f;
#pragma unroll
                for (int j = 0; j < 4; j++) {
                    int gn = n0 + j * 16 + sl;
                    float v = acc[i][j][reg];
                    if (gn < XL_END) {
                        p8[(size_t)gm * SL8s + gn] = to_fp8(v);
                        axl += attw[gn] * v;
                    } else if (gn < XR_END) {
                        pb[(size_t)gm * SRBs + (gn - XL_END)] = __float2bfloat16(v);
                        axr += attw[gn - XL_END] * v;
                    } else {
                        if constexpr (EPI == 1) {
                            if (gn < 620)      pb[(size_t)gm * 320 + (gn - 300)] = __float2bfloat16(0.f);
                            else if (gn < 624) p8[(size_t)gm * 304 + (gn - 320)] = 0;
                        } else {
                            if (gn < 212)      p8[(size_t)gm * 112 + (gn - 100)] = 0;
                            else if (gn < 240) pb[(size_t)gm * 128 + (gn - 112)] = __float2bfloat16(0.f);
                        }
                    }
                }
                if (hasXl) {
#pragma unroll
                    for (int o = 1; o < 16; o <<= 1) axl += __shfl_xor(axl, o, 64);
                    if (sl == 0) atomicAdd(&sxl[gm], 0.6f * axl);
                }
                if (hasXr) {
#pragma unroll
                    for (int o = 1; o < 16; o <<= 1) axr += __shfl_xor(axr, o, 64);
                    if (sl == 0) atomicAdd(&sxr[gm], 0.6f * axr);
                }
            }
        }
    } else {
#pragma unroll
        for (int i = 0; i < 2; i++) {
#pragma unroll
            for (int j = 0; j < 4; j++) {
#pragma unroll
                for (int reg = 0; reg < 4; reg++) {
                    int gm = m0 + w * 32 + i * 16 + q * 4 + reg;
                    int gn = n0 + j * 16 + sl;
                    if (gm >= M) continue;
                    float v = acc[i][j][reg];
                    if constexpr (EPI == 3) {
                        if (gn < 200) {
                            int cn = gn < 100 ? gn : gn - 100;
                            float val = fmaxf(v + bias[gn], 0.f) + h2[(size_t)gm * 100 + cn];
                            if (gn < 100) C[(size_t)gm * 100 + gn] = val;
                            else p8[(size_t)gm * 128 + (gn - 100)] = to_fp8(val);
                        } else if (gn < 228) {
                            p8[(size_t)gm * 128 + (gn - 100)] = 0;
                        }
                    } else {
                        store_v(&C[(size_t)gm * ldc + gn], v);
                    }
                }
            }
        }
    }
}

// ---------------------------------------------------------------------------
// GATv2 edge+aggregate on fp8 xl table (L2-resident) + bf16 xr.
// Score via leaky identity: leaky(t) = 0.6t + 0.4|t| =>
//   p = sxl[src] + sxr[dst] + sum_f (0.4*att_f)*|xl_f + xr_f|
//   (per feature-slot: add + fma-with-|.|-modifier + acc-fma = 3 VALU ops)
// Quad-parallel (4 edges/wave), software-pipelined prefetch of next
// iteration's ssrc + rows + sxl. Two waves per node, LDS combine.
// NT loads for one-touch streams; REGULAR stores (outputs feed next GEMM).
// ---------------------------------------------------------------------------
template <int F, int NJ, int SL8, int SRB, int SOUT, int JSL, typename TOUT>
__global__ __launch_bounds__(256) void gat_f8_kernel(
    const unsigned char* __restrict__ xl8, const __hip_bfloat16* __restrict__ xrb,
    const float* __restrict__ att, const float* __restrict__ bias,
    const float* __restrict__ sxl, const float* __restrict__ sxr,
    const int* __restrict__ off, const int* __restrict__ ssrc,
    TOUT* __restrict__ out, int n) {
    __shared__ float sden[2];
    __shared__ float sacc[2][NJ * 64];
    const int t = threadIdx.x;
    const int lane = t & 63;
    const int sl = lane & 15, q = lane >> 4;
    const int half = (t >> 6) & 1;
    const int pairIdx = t >> 7;
    int wid = blockIdx.x * 2 + pairIdx;
    if (wid >= n) wid = n - 1;          // clamp; duplicate writes identical

    float att4[NJ * 4], xrv[NJ * 4], acc[NJ * 4];
    const unsigned* xru = (const unsigned*)xrb + (size_t)wid * (SRB / 2);
#pragma unroll
    for (int j = 0; j < NJ; j++) {
        const int f0 = sl * 4 + j * 64;
        if (f0 < F) {
            float4 a4 = *(const float4*)(att + f0);
            att4[j * 4 + 0] = 0.4f * a4.x; att4[j * 4 + 1] = 0.4f * a4.y;
            att4[j * 4 + 2] = 0.4f * a4.z; att4[j * 4 + 3] = 0.4f * a4.w;
        } else {
            att4[j * 4 + 0] = att4[j * 4 + 1] = att4[j * 4 + 2] = att4[j * 4 + 3] = 0.f;
        }
        unsigned u0 = __builtin_nontemporal_load(xru + (f0 >> 1));
        unsigned u1 = __builtin_nontemporal_load(xru + (f0 >> 1) + 1);
        xrv[j * 4 + 0] = blo(u0); xrv[j * 4 + 1] = bhi(u0);
        xrv[j * 4 + 2] = blo(u1); xrv[j * 4 + 3] = bhi(u1);
        acc[j * 4 + 0] = acc[j * 4 + 1] = acc[j * 4 + 2] = acc[j * 4 + 3] = 0.f;
    }
    const float pbase = sxr[wid];

    const int s0 = off[wid], s1 = off[wid + 1];
    const int h0 = (s1 - s0) >> 1;      // wave0: self + h0 edges; wave1: rest
    const int eb = half ? (s0 + h0) : (s0 - 1);
    const int ee = half ? s1 : (s0 + h0);
    float den = 0.f;

    // ---- prologue: load iteration 0's index + rows + sxl ----
    unsigned u[NJ];
    float sx;
    {
        int eq = eb + q;
        int src = wid;
        if (eq >= s0 && eq < ee) src = __builtin_nontemporal_load(ssrc + eq);
        const unsigned char* row = xl8 + (size_t)src * SL8;
#pragma unroll
        for (int j = 0; j < NJ; j++) {
            const bool ld = (j < NJ - 1) || (sl < JSL);
            u[j] = ld ? *(const unsigned*)(row + sl * 4 + j * 64) : 0u;
        }
        sx = sxl[src];
    }

    for (int e0 = eb; e0 < ee; e0 += 4) {
        const bool act = (e0 + q) < ee;
        // ---- prefetch next iteration (harmless self-row if past end) ----
        unsigned un[NJ];
        float sxn;
        {
            int eq1 = e0 + 4 + q;
            int src1 = wid;
            if (eq1 >= s0 && eq1 < ee) src1 = __builtin_nontemporal_load(ssrc + eq1);
            const unsigned char* row1 = xl8 + (size_t)src1 * SL8;
#pragma unroll
            for (int j = 0; j < NJ; j++) {
                const bool ld = (j < NJ - 1) || (sl < JSL);
                un[j] = ld ? *(const unsigned*)(row1 + sl * 4 + j * 64) : 0u;
            }
            sxn = sxl[src1];
        }
        // ---- process current ----
        float xlv[NJ * 4];
        float p = (sl == 0) ? (pbase + sx) : 0.f;
#pragma unroll
        for (int j = 0; j < NJ; j++) {
            floatx2 lo = __builtin_amdgcn_cvt_pk_f32_fp8((int)u[j], false);
            floatx2 hi = __builtin_amdgcn_cvt_pk_f32_fp8((int)u[j], true);
            float v[4] = {lo.x, lo.y, hi.x, hi.y};
#pragma unroll
            for (int cc = 0; cc < 4; cc++) {
                xlv[j * 4 + cc] = v[cc];
                float s = v[cc] + xrv[j * 4 + cc];
                p = fmaf(att4[j * 4 + cc], fabsf(s), p);
            }
        }
        p += __shfl_xor(p, 1, 64);
        p += __shfl_xor(p, 2, 64);
        p += __shfl_xor(p, 4, 64);
        p += __shfl_xor(p, 8, 64);
        float ex = act ? expf(p) : 0.f;
        den += ex;
#pragma unroll
        for (int i = 0; i < NJ * 4; i++) acc[i] += ex * xlv[i];
        // ---- rotate ----
#pragma unroll
        for (int j = 0; j < NJ; j++) u[j] = un[j];
        sx = sxn;
    }

    // cross-quad butterfly
#pragma unroll
    for (int o = 16; o <= 32; o <<= 1) {
        den += __shfl_xor(den, o, 64);
#pragma unroll
        for (int i = 0; i < NJ * 4; i++) acc[i] += __shfl_xor(acc[i], o, 64);
    }

    if (half == 1 && lane < 16) {
        if (lane == 0) sden[pairIdx] = den;
#pragma unroll
        for (int j = 0; j < NJ; j++)
            *(float4*)(&sacc[pairIdx][sl * 4 + j * 64]) =
                make_float4(acc[j * 4 + 0], acc[j * 4 + 1], acc[j * 4 + 2], acc[j * 4 + 3]);
    }
    __syncthreads();
    if (half == 0 && lane < 16) {
        den += sden[pairIdx];
        const float inv = 1.f / (den + 1e-16f);
#pragma unroll
        for (int j = 0; j < NJ; j++) {
            const int f0 = sl * 4 + j * 64;
            if (f0 >= SOUT) continue;
            float4 o4 = *(float4*)(&sacc[pairIdx][f0]);
            float vv[4] = {acc[j * 4 + 0] + o4.x, acc[j * 4 + 1] + o4.y,
                           acc[j * 4 + 2] + o4.z, acc[j * 4 + 3] + o4.w};
            float r[4];
#pragma unroll
            for (int cc = 0; cc < 4; cc++) {
                const int f = f0 + cc;
                float v = 0.f;
                if (f < F) v = fmaxf(vv[cc] * inv + bias[f], 0.f);
                r[cc] = v;
            }
            if constexpr (sizeof(TOUT) == 4) {   // float out (regular stores)
                *(float4*)((float*)out + (size_t)wid * SOUT + f0) =
                    make_float4(r[0], r[1], r[2], r[3]);
            } else {                             // bf16 out (regular stores)
                unsigned* op = (unsigned*)out + (size_t)wid * (SOUT / 2) + (f0 >> 1);
                op[0] = pk2bf(r[0], r[1]);
                op[1] = pk2bf(r[2], r[3]);
            }
        }
    }
}

// ---------------------------------------------------------------------------
// Layer-3 projections: xl3 = xo @ Wl3, xr3 = xo @ Wr3   (K=100)
// ---------------------------------------------------------------------------
__global__ __launch_bounds__(256) void gemm_vec1_kernel(
    const float* __restrict__ xo, const float* __restrict__ wl,
    const float* __restrict__ wr, float* __restrict__ xl3,
    float* __restrict__ xr3, int M, int ldx) {
    const int wid = blockIdx.x * 4 + (threadIdx.x >> 6);
    const int lane = threadIdx.x & 63;
    if (wid >= M) return;
    float a = 0.f, b = 0.f;
    for (int f = lane; f < 100; f += 64) {
        float v = xo[(size_t)wid * ldx + f];
        a += v * wl[f];
        b += v * wr[f];
    }
    a = wave_reduce_sum(a);
    b = wave_reduce_sum(b);
    if (lane == 0) { xl3[wid] = a; xr3[wid] = b; }
}

// ---------------------------------------------------------------------------
// Layer-3 GAT (F=1): wave per node, lanes parallel over edges.
// ---------------------------------------------------------------------------
__global__ __launch_bounds__(256) void gat3_kernel(
    const float* __restrict__ xl3, const float* __restrict__ xr3,
    const float* __restrict__ att3, const float* __restrict__ b3,
    const int* __restrict__ off, const int* __restrict__ ssrc,
    float* __restrict__ out, int n) {
    const int wid = blockIdx.x * 4 + (threadIdx.x >> 6);
    const int lane = threadIdx.x & 63;
    if (wid >= n) return;
    const float xrv = xr3[wid];
    const float att = att3[0];
    float num = 0.f, den = 0.f;
    const int s0 = off[wid], s1 = off[wid + 1];
    for (int e = s0 - 1 + lane; e < s1; e += 64) {
        int src = (e < s0) ? wid : ssrc[e];
        float xlv = xl3[src];
        float t = xlv + xrv;
        float g = t > 0.f ? t : 0.2f * t;
        float ex = expf(g * att);
        den += ex;
        num += ex * xlv;
    }
    num = wave_reduce_sum(num);
    den = wave_reduce_sum(den);
    if (lane == 0) out[wid] = num / (den + 1e-16f) + b3[0];
}

// ---------------------------------------------------------------------------
// Link-prediction loss on fp8 z [N,128]. Per-block partials (no same-address
// atomics — they serialized cross-XCD at ~15 ns each, R8 evidence).
// ---------------------------------------------------------------------------
__global__ __launch_bounds__(256) void loss_kernel(
    const unsigned char* __restrict__ z8, const int* __restrict__ pos,
    const int* __restrict__ neg, float* __restrict__ part, int nb, int E) {
    const int lane = threadIdx.x & 63;
    const int sl = lane & 15;
    const int wlocal = threadIdx.x >> 6;
    const int q = lane >> 4;
    const int nq = gridDim.x * 16;
    const int qid = (blockIdx.x * 4 + wlocal) * 4 + q;
    const int total = 2 * E;
    float psum = 0.f, nsum = 0.f;

    for (int base = qid; base < total; base += 4 * nq) {
        uint2 au[4], bu[4];
        bool act[4], isN[4];
#pragma unroll
        for (int s = 0; s < 4; s++) {
            int it = base + s * nq;
            act[s] = it < total;
            int itc = act[s] ? it : 0;
            isN[s] = itc >= E;
            int e = isN[s] ? itc - E : itc;
            const int* ei = isN[s] ? neg : pos;
            int u = ei[e], v = ei[E + e];
            au[s] = *(const uint2*)(z8 + (size_t)u * 128 + sl * 8);
            bu[s] = *(const uint2*)(z8 + (size_t)v * 128 + sl * 8);
        }
#pragma unroll
        for (int s = 0; s < 4; s++) {
            floatx2 a0 = __builtin_amdgcn_cvt_pk_f32_fp8((int)au[s].x, false);
            floatx2 a1 = __builtin_amdgcn_cvt_pk_f32_fp8((int)au[s].x, true);
            floatx2 a2 = __builtin_amdgcn_cvt_pk_f32_fp8((int)au[s].y, false);
            floatx2 a3 = __builtin_amdgcn_cvt_pk_f32_fp8((int)au[s].y, true);
            floatx2 b0 = __builtin_amdgcn_cvt_pk_f32_fp8((int)bu[s].x, false);
            floatx2 b1 = __builtin_amdgcn_cvt_pk_f32_fp8((int)bu[s].x, true);
            floatx2 b2 = __builtin_amdgcn_cvt_pk_f32_fp8((int)bu[s].y, false);
            floatx2 b3 = __builtin_amdgcn_cvt_pk_f32_fp8((int)bu[s].y, true);
            float p = a0.x * b0.x + a0.y * b0.y + a1.x * b1.x + a1.y * b1.y
                    + a2.x * b2.x + a2.y * b2.y + a3.x * b3.x + a3.y * b3.y;
            p += __shfl_xor(p, 1, 64);
            p += __shfl_xor(p, 2, 64);
            p += __shfl_xor(p, 4, 64);
            p += __shfl_xor(p, 8, 64);
            if (sl == 0 && act[s]) {
                float sig = 1.f / (1.f + expf(-p));
                if (isN[s]) nsum += logf(1.f - sig + 1e-15f);
                else        psum += logf(sig + 1e-15f);
            }
        }
    }
    float pw = wave_reduce_sum(psum);
    float nw = wave_reduce_sum(nsum);
    __shared__ float sp[4], sn[4];
    if (lane == 0) { sp[wlocal] = pw; sn[wlocal] = nw; }
    __syncthreads();
    if (threadIdx.x == 0) {
        part[blockIdx.x]      = sp[0] + sp[1] + sp[2] + sp[3];
        part[nb + blockIdx.x] = sn[0] + sn[1] + sn[2] + sn[3];
    }
}

// Final reduction of per-block partials + scalar outputs.
__global__ __launch_bounds__(1024) void finalize_kernel(
    const float* __restrict__ part, int nb,
    const float* __restrict__ c1, const float* __restrict__ c2,
    float* __restrict__ out, int n, int E) {
    __shared__ float sp[16], sn[16];
    const int tid = threadIdx.x, lane = tid & 63, w = tid >> 6;
    float p = 0.f, q = 0.f;
    for (int i = tid; i < nb; i += 1024) { p += part[i]; q += part[nb + i]; }
    p = wave_reduce_sum(p);
    q = wave_reduce_sum(q);
    if (lane == 0) { sp[w] = p; sn[w] = q; }
    __syncthreads();
    if (tid == 0) {
        float tp = 0.f, tq = 0.f;
#pragma unroll
        for (int i = 0; i < 16; i++) { tp += sp[i]; tq += sn[i]; }
        out[n]     = -(tp + tq) / (float)E;
        out[n + 1] = c1[0];
        out[n + 2] = c2[0];
    }
}

// ---------------------------------------------------------------------------
extern "C" void kernel_launch(void* const* d_in, const int* in_sizes, int n_in,
                              void* d_out, int out_size, void* d_ws, size_t ws_size,
                              hipStream_t stream) {
    const float* x      = (const float*)d_in[0];
    const int*   ei     = (const int*)d_in[1];
    const int*   nei    = (const int*)d_in[2];
    const float* Wl1    = (const float*)d_in[3];
    const float* Wr1    = (const float*)d_in[4];
    const float* att1   = (const float*)d_in[5];
    const float* b1     = (const float*)d_in[6];
    const float* Wl2    = (const float*)d_in[7];
    const float* Wr2    = (const float*)d_in[8];
    const float* att2   = (const float*)d_in[9];
    const float* b2     = (const float*)d_in[10];
    const float* Wl3    = (const float*)d_in[11];
    const float* Wr3    = (const float*)d_in[12];
    const float* att3   = (const float*)d_in[13];
    const float* b3     = (const float*)d_in[14];
    const float* Wlin1  = (const float*)d_in[15];
    const float* blin1  = (const float*)d_in[16];
    const float* Wlin2  = (const float*)d_in[17];
    const float* blin2  = (const float*)d_in[18];
    const float* c1     = (const float*)d_in[19];
    const float* c2     = (const float*)d_in[20];
    float* out = (float*)d_out;

    const int E = in_sizes[1] / 2;   // 504378
    const int N = NODES;
    const int LOSS_BLOCKS = 4096;

    // ---- workspace carve (bytes), ~39.2 MB, live windows disjoint ----
    char* ws = (char*)d_ws;
    unsigned char*  xl8  = (unsigned char*)(ws + 0);          // [N,304] fp8 (4.14MB < 4MiB L2)
    unsigned char*  xl28 = (unsigned char*)(ws + 0);          // [N,112] fp8 (after gat1)
    __hip_bfloat16* xrb  = (__hip_bfloat16*)(ws + 4194304);   // [N,320] bf16 (L1)
    __hip_bfloat16* xr2b = (__hip_bfloat16*)(ws + 4194304);   // [N,128] bf16 (after gat1)
    float*          xo   = (float*)(ws + 4194304);            // [N,100] f32 (after gat2)
    unsigned char*  z8   = (unsigned char*)(ws + 9645312);    // [N,128] fp8
    __hip_bfloat16* h1b  = (__hip_bfloat16*)(ws + 12915712);  // [N,320] bf16 (gat1 -> L2 GEMM)
    float*          h2   = (float*)(ws + 12915712);           // [N,100] f32 (after L2 GEMM)
    __hip_bfloat16* xb   = (__hip_bfloat16*)(ws + 21637120);  // [N,512] bf16
    __hip_bfloat16* W1T  = (__hip_bfloat16*)(ws + 35591168);  // [640,512]
    __hip_bfloat16* W2T  = (__hip_bfloat16*)(ws + 36246528);  // [256,320]
    __hip_bfloat16* WsT  = (__hip_bfloat16*)(ws + 36410368);  // [256,512]
    float*          bcat = (float*)(ws + 36672512);           // [256]
    float*          xl3  = (float*)(ws + 36673536);
    float*          xr3  = (float*)(ws + 36728064);
    int*            ioff = (int*)(ws + 36782592);             // N+1
    int*            cur  = (int*)(ws + 36837376);             // N
    int*            ssrc = (int*)(ws + 36892160);             // E
    float*          part = (float*)(ws + 38909952);           // [2*LOSS_BLOCKS] = 32KB
    float*          sxl1 = (float*)(ws + 38942720);           // [N] f32 — contiguous block:
    float*          sxr1 = (float*)(ws + 38997248);           // [N]
    float*          sxl2 = (float*)(ws + 39051776);           // [N]
    float*          sxr2 = (float*)(ws + 39106304);           // [N]

    hipMemsetAsync(cur, 0, sizeof(int) * N, stream);
    hipMemsetAsync(sxl1, 0, sizeof(float) * 4 * 54527, stream);  // sxl1..sxr2 contiguous

    // ---- CSR build ----
    hist_kernel<<<(E + 255) / 256, 256, 0, stream>>>(ei + E, cur, E);
    scan_kernel<<<1, 1024, 0, stream>>>(cur, ioff, N);
    scatter_kernel<<<(E + 255) / 256, 256, 0, stream>>>(ei, ei + E, cur, ssrc, E);

    // ---- pack inputs/weights (one fused launch) ----
    convert_all_kernel<<<(540928 + N * 128 + 255) / 256, 256, 0, stream>>>(
        x, Wl1, Wr1, Wl2, Wr2, Wlin1, Wlin2, blin1, blin2,
        W1T, W2T, WsT, bcat, xb, N);

    // ---- layer 1: GEMM -> xl8 fp8 [N,304] + xrb bf16 [N,320] + sxl1/sxr1 ----
    mfma_gemm<1, __hip_bfloat16><<<dim3(10, 107), 256, 0, stream>>>(
        xb, W1T, (__hip_bfloat16*)nullptr, nullptr, nullptr, xl8, xrb,
        att1, sxl1, sxr1, N, 512, 640, 0);
    gat_f8_kernel<300, 5, 304, 320, 320, 11, __hip_bfloat16>
        <<<(N + 1) / 2, 256, 0, stream>>>(xl8, xrb, att1, b1, sxl1, sxr1, ioff, ssrc, h1b, N);

    // ---- layer 2: GEMM -> xl28 fp8 [N,112] + xr2b bf16 [N,128] + sxl2/sxr2 ----
    mfma_gemm<2, __hip_bfloat16><<<dim3(4, 107), 256, 0, stream>>>(
        h1b, W2T, (__hip_bfloat16*)nullptr, nullptr, nullptr, xl28, xr2b,
        att2, sxl2, sxr2, N, 320, 256, 0);
    gat_f8_kernel<100, 2, 112, 128, 100, 9, float>
        <<<(N + 1) / 2, 256, 0, stream>>>(xl28, xr2b, att2, b2, sxl2, sxr2, ioff, ssrc, h2, N);

    // ---- skip connections: xo f32 [N,100], z8 fp8 [N,128] ----
    mfma_gemm<3, float><<<dim3(4, 107), 256, 0, stream>>>(
        xb, WsT, xo, bcat, h2, z8, nullptr, nullptr, nullptr, nullptr, N, 512, 256, 0);

    // ---- reconstruction loss (per-block partials, no atomics) ----
    loss_kernel<<<LOSS_BLOCKS, 256, 0, stream>>>(z8, ei, nei, part, LOSS_BLOCKS, E);

    // ---- layer 3 ----
    gemm_vec1_kernel<<<(N + 3) / 4, 256, 0, stream>>>(xo, Wl3, Wr3, xl3, xr3, N, 100);
    gat3_kernel<<<(N + 3) / 4, 256, 0, stream>>>(xl3, xr3, att3, b3, ioff, ssrc, out, N);

    finalize_kernel<<<1, 1024, 0, stream>>>(part, LOSS_BLOCKS, c1, c2, out, N, E);
}

// Round 14
// 388.589 us; speedup vs baseline: 1.0691x; 1.0691x over previous
//
#include <hip/hip_runtime.h>
#include <hip/hip_bf16.h>

#define NODES 13627
#define DIM   500

typedef short short8 __attribute__((ext_vector_type(8)));
typedef float f32x4 __attribute__((ext_vector_type(4)));
typedef float floatx2 __attribute__((ext_vector_type(2)));

__device__ inline float wave_reduce_sum(float v) {
#pragma unroll
    for (int o = 32; o > 0; o >>= 1) v += __shfl_xor(v, o, 64);
    return v;
}

__device__ inline void store_v(float* p, float v) { *p = v; }
__device__ inline void store_v(__hip_bfloat16* p, float v) { *p = __float2bfloat16(v); }

// bf16 (packed pair in uint) -> f32, exact
__device__ inline float blo(unsigned w) { unsigned t = w << 16;        return __builtin_bit_cast(float, t); }
__device__ inline float bhi(unsigned w) { unsigned t = w & 0xffff0000u; return __builtin_bit_cast(float, t); }

// fp8 e4m3 (OCP, HW convert)
__device__ inline unsigned char to_fp8(float v) {
    int r = __builtin_amdgcn_cvt_pk_fp8_f32(v, v, 0, false);
    return (unsigned char)(r & 0xff);
}

// pack two floats into bf16x2 word (RNE)
__device__ inline unsigned pk2bf(float a, float b) {
    unsigned la = (unsigned)__builtin_bit_cast(unsigned short, __float2bfloat16(a));
    unsigned hb = (unsigned)__builtin_bit_cast(unsigned short, __float2bfloat16(b));
    return la | (hb << 16);
}

struct b4 { __hip_bfloat16 a, b, c, d; };

// ---------------------------------------------------------------------------
// CSR build: histogram -> scan -> scatter
// ---------------------------------------------------------------------------
__global__ __launch_bounds__(256) void hist_kernel(const int* __restrict__ dst,
                                                   int* __restrict__ cnt, int E) {
    int i = blockIdx.x * blockDim.x + threadIdx.x;
    if (i < E) atomicAdd(&cnt[dst[i]], 1);
}

__global__ __launch_bounds__(1024) void scan_kernel(int* __restrict__ cnt_cur,
                                                    int* __restrict__ off, int n) {
    __shared__ int wsum[16];
    const int tid = threadIdx.x, lane = tid & 63, w = tid >> 6;
    int carry = 0;
    for (int base = 0; base < n; base += 1024) {
        int i = base + tid;
        int v = (i < n) ? cnt_cur[i] : 0;
        int s = v;
#pragma unroll
        for (int o = 1; o < 64; o <<= 1) {
            int t = __shfl_up(s, o, 64);
            if (lane >= o) s += t;
        }
        if (lane == 63) wsum[w] = s;
        __syncthreads();
        if (w == 0 && lane < 16) {
            int x = wsum[lane];
            int sx = x;
#pragma unroll
            for (int o = 1; o < 16; o <<= 1) {
                int t = __shfl_up(sx, o, 64);
                if (lane >= o) sx += t;
            }
            wsum[lane] = sx;
        }
        __syncthreads();
        int wo = (w == 0) ? 0 : wsum[w - 1];
        int total = wsum[15];
        int excl = carry + wo + (s - v);
        if (i < n) { off[i] = excl; cnt_cur[i] = excl; }
        carry += total;
        __syncthreads();
    }
    if (tid == 0) off[n] = carry;
}

__global__ __launch_bounds__(256) void scatter_kernel(const int* __restrict__ src,
                                                      const int* __restrict__ dst,
                                                      int* __restrict__ cur,
                                                      int* __restrict__ ssrc, int E) {
    int i = blockIdx.x * blockDim.x + threadIdx.x;
    if (i < E) {
        int p = atomicAdd(&cur[dst[i]], 1);
        ssrc[p] = src[i];
    }
}

// ---------------------------------------------------------------------------
// Fused conversion / packing (weights + bias + x) in ONE launch.
// ---------------------------------------------------------------------------
__global__ __launch_bounds__(256) void convert_all_kernel(
    const float* __restrict__ x,
    const float* __restrict__ Wl1, const float* __restrict__ Wr1,
    const float* __restrict__ Wl2, const float* __restrict__ Wr2,
    const float* __restrict__ Ws1, const float* __restrict__ Ws2,
    const float* __restrict__ bs1, const float* __restrict__ bs2,
    __hip_bfloat16* __restrict__ W1T, __hip_bfloat16* __restrict__ W2T,
    __hip_bfloat16* __restrict__ WsT, float* __restrict__ bcat,
    __hip_bfloat16* __restrict__ xb, int M) {
    int i = blockIdx.x * 256 + threadIdx.x;
    if (i < 327680) {
        int n = i >> 9, k = i & 511;
        float v = 0.f;
        if (k < 500) {
            if (n < 300) v = Wl1[k * 300 + n];
            else if (n < 600) v = Wr1[k * 300 + n - 300];
        }
        W1T[i] = __float2bfloat16(v);
    } else if (i < 409600) {
        int j = i - 327680;
        int n = j / 320, k = j - n * 320;
        float v = 0.f;
        if (k < 300) {
            if (n < 100) v = Wl2[k * 100 + n];
            else if (n < 200) v = Wr2[k * 100 + n - 100];
        }
        W2T[j] = __float2bfloat16(v);
    } else if (i < 540672) {
        int j = i - 409600;
        int n = j >> 9, k = j & 511;
        float v = 0.f;
        if (k < 500) {
            if (n < 100) v = Ws1[k * 100 + n];
            else if (n < 200) v = Ws2[k * 100 + n - 100];
        }
        WsT[j] = __float2bfloat16(v);
    } else if (i < 540928) {
        int n = i - 540672;
        float v = 0.f;
        if (n < 100) v = bs1[n];
        else if (n < 200) v = bs2[n - 100];
        bcat[n] = v;
    } else {
        int j = i - 540928;
        if (j >= M * 128) return;
        int m = j >> 7, k = (j & 127) << 2;
        b4 o;
        if (k < 500) {
            float4 v = *(const float4*)(x + (size_t)m * 500 + k);
            o.a = __float2bfloat16(v.x); o.b = __float2bfloat16(v.y);
            o.c = __float2bfloat16(v.z); o.d = __float2bfloat16(v.w);
        } else {
            o.a = o.b = o.c = o.d = __float2bfloat16(0.f);
        }
        *(b4*)(xb + (size_t)m * 512 + k) = o;
    }
}

// ---------------------------------------------------------------------------
// bf16 MFMA GEMM: C[M,Nn] = A[M,Kp] @ BT[Nn,Kp]^T   (BM=128, BN=64, BK=32)
// EPI=1: layer-1 pack; EPI=2: layer-2 pack; EPI=3: skip epilogue
// ---------------------------------------------------------------------------
template <int EPI, typename TC>
__global__ __launch_bounds__(256) void mfma_gemm(
    const __hip_bfloat16* __restrict__ A, const __hip_bfloat16* __restrict__ BT,
    TC* __restrict__ C, const float* __restrict__ bias, const float* __restrict__ h2,
    unsigned char* __restrict__ p8, __hip_bfloat16* __restrict__ pb,
    int M, int Kp, int Nn, int ldc) {
    __shared__ short AsF[8 * 64 * 8];
    __shared__ short BsF[4 * 64 * 8];
    const int t = threadIdx.x;
    const int w = t >> 6, lane = t & 63;
    const int c = t & 3, rr = t >> 2;
    const int m0 = blockIdx.y * 128, n0 = blockIdx.x * 64;

    f32x4 acc[2][4];
#pragma unroll
    for (int i = 0; i < 2; i++)
#pragma unroll
        for (int j = 0; j < 4; j++) acc[i][j] = (f32x4){0.f, 0.f, 0.f, 0.f};

    for (int k0 = 0; k0 < Kp; k0 += 32) {
#pragma unroll
        for (int r = 0; r < 2; r++) {
            int m = r * 64 + rr;
            int gm = m0 + m; if (gm >= M) gm = M - 1;
            float4 v = *(const float4*)(A + (size_t)gm * Kp + k0 + c * 8);
            int mi = m >> 4, sl = m & 15;
            *(float4*)(&AsF[(mi * 64 + c * 16 + sl) * 8]) = v;
        }
        {
            int n = rr;
            float4 v = *(const float4*)(BT + (size_t)(n0 + n) * Kp + k0 + c * 8);
            int ni = n >> 4, sl = n & 15;
            *(float4*)(&BsF[(ni * 64 + c * 16 + sl) * 8]) = v;
        }
        __syncthreads();
        short8 a0 = *(const short8*)(&AsF[((w * 2 + 0) * 64 + lane) * 8]);
        short8 a1 = *(const short8*)(&AsF[((w * 2 + 1) * 64 + lane) * 8]);
#pragma unroll
        for (int j = 0; j < 4; j++) {
            short8 b = *(const short8*)(&BsF[(j * 64 + lane) * 8]);
            acc[0][j] = __builtin_amdgcn_mfma_f32_16x16x32_bf16(a0, b, acc[0][j], 0, 0, 0);
            acc[1][j] = __builtin_amdgcn_mfma_f32_16x16x32_bf16(a1, b, acc[1][j], 0, 0, 0);
        }
        __syncthreads();
    }

    const int q = lane >> 4, sl = lane & 15;
#pragma unroll
    for (int i = 0; i < 2; i++) {
#pragma unroll
        for (int j = 0; j < 4; j++) {
#pragma unroll
            for (int reg = 0; reg < 4; reg++) {
                int gm = m0 + w * 32 + i * 16 + q * 4 + reg;
                int gn = n0 + j * 16 + sl;
                if (gm >= M) continue;
                float v = acc[i][j][reg];
                if constexpr (EPI == 1) {
                    if (gn < 300)       p8[(size_t)gm * 304 + gn] = to_fp8(v);
                    else if (gn < 600)  pb[(size_t)gm * 320 + (gn - 300)] = __float2bfloat16(v);
                    else if (gn < 620)  pb[(size_t)gm * 320 + (gn - 300)] = __float2bfloat16(0.f);
                    else if (gn < 624)  p8[(size_t)gm * 304 + (gn - 320)] = 0;
                } else if constexpr (EPI == 2) {
                    if (gn < 100)       p8[(size_t)gm * 112 + gn] = to_fp8(v);
                    else if (gn < 200)  pb[(size_t)gm * 128 + (gn - 100)] = __float2bfloat16(v);
                    else if (gn < 212)  p8[(size_t)gm * 112 + (gn - 100)] = 0;
                    else if (gn < 240)  pb[(size_t)gm * 128 + (gn - 112)] = __float2bfloat16(0.f);
                } else if constexpr (EPI == 3) {
                    if (gn < 200) {
                        int cn = gn < 100 ? gn : gn - 100;
                        float val = fmaxf(v + bias[gn], 0.f) + h2[(size_t)gm * 100 + cn];
                        if (gn < 100) C[(size_t)gm * 100 + gn] = val;
                        else p8[(size_t)gm * 128 + (gn - 100)] = to_fp8(val);
                    } else if (gn < 228) {
                        p8[(size_t)gm * 128 + (gn - 100)] = 0;
                    }
                } else {
                    store_v(&C[(size_t)gm * ldc + gn], v);
                }
            }
        }
    }
}

// ---------------------------------------------------------------------------
// GATv2 edge+aggregate on fp8 xl table (L2-resident) + bf16 xr.
// Quad-parallel (4 edges/wave), two waves per node, LDS combine,
// software-pipelined next-iteration prefetch (R12 structure).
// INNER LOOP IN PACKED f32x2: fp8 decode already yields floatx2 pairs;
// add/max/fma on f32x2 lets the compiler emit dual-issue v_pk_*_f32.
// ---------------------------------------------------------------------------
template <int F, int NJ, int SL8, int SRB, int SOUT, int JSL, typename TOUT>
__global__ __launch_bounds__(256) void gat_f8_kernel(
    const unsigned char* __restrict__ xl8, const __hip_bfloat16* __restrict__ xrb,
    const float* __restrict__ att, const float* __restrict__ bias,
    const int* __restrict__ off, const int* __restrict__ ssrc,
    TOUT* __restrict__ out, int n) {
    __shared__ float sden[2];
    __shared__ float sacc[2][NJ * 64];
    const int t = threadIdx.x;
    const int lane = t & 63;
    const int sl = lane & 15, q = lane >> 4;
    const int half = (t >> 6) & 1;
    const int pairIdx = t >> 7;
    int wid = blockIdx.x * 2 + pairIdx;
    if (wid >= n) wid = n - 1;          // clamp; duplicate writes identical

    floatx2 attv[NJ * 2], xrv[NJ * 2], acc[NJ * 2];
    const unsigned* xru = (const unsigned*)xrb + (size_t)wid * (SRB / 2);
#pragma unroll
    for (int j = 0; j < NJ; j++) {
        const int f0 = sl * 4 + j * 64;
        if (f0 < F) {
            float4 a4 = *(const float4*)(att + f0);
            attv[j * 2 + 0] = (floatx2){a4.x, a4.y};
            attv[j * 2 + 1] = (floatx2){a4.z, a4.w};
        } else {
            attv[j * 2 + 0] = (floatx2){0.f, 0.f};
            attv[j * 2 + 1] = (floatx2){0.f, 0.f};
        }
        unsigned u0 = __builtin_nontemporal_load(xru + (f0 >> 1));
        unsigned u1 = __builtin_nontemporal_load(xru + (f0 >> 1) + 1);
        xrv[j * 2 + 0] = (floatx2){blo(u0), bhi(u0)};
        xrv[j * 2 + 1] = (floatx2){blo(u1), bhi(u1)};
        acc[j * 2 + 0] = (floatx2){0.f, 0.f};
        acc[j * 2 + 1] = (floatx2){0.f, 0.f};
    }

    const int s0 = off[wid], s1 = off[wid + 1];
    const int h0 = (s1 - s0) >> 1;      // wave0: self + h0 edges; wave1: rest
    const int eb = half ? (s0 + h0) : (s0 - 1);
    const int ee = half ? s1 : (s0 + h0);
    float den = 0.f;

    // ---- prologue: load iteration 0's indices + rows ----
    unsigned u[NJ];
    {
        int eq = eb + q;
        int src = wid;
        if (eq >= s0 && eq < ee) src = __builtin_nontemporal_load(ssrc + eq);
        const unsigned char* row = xl8 + (size_t)src * SL8;
#pragma unroll
        for (int j = 0; j < NJ; j++) {
            const bool ld = (j < NJ - 1) || (sl < JSL);
            u[j] = ld ? *(const unsigned*)(row + sl * 4 + j * 64) : 0u;
        }
    }

    for (int e0 = eb; e0 < ee; e0 += 4) {
        const bool act = (e0 + q) < ee;
        // ---- prefetch next iteration (harmless self-row if past end) ----
        unsigned un[NJ];
        {
            int eq1 = e0 + 4 + q;
            int src1 = wid;
            if (eq1 >= s0 && eq1 < ee) src1 = __builtin_nontemporal_load(ssrc + eq1);
            const unsigned char* row1 = xl8 + (size_t)src1 * SL8;
#pragma unroll
            for (int j = 0; j < NJ; j++) {
                const bool ld = (j < NJ - 1) || (sl < JSL);
                un[j] = ld ? *(const unsigned*)(row1 + sl * 4 + j * 64) : 0u;
            }
        }
        // ---- process current (packed f32x2) ----
        floatx2 xlv[NJ * 2];
        floatx2 p2 = (floatx2){0.f, 0.f};
#pragma unroll
        for (int j = 0; j < NJ; j++) {
            floatx2 lo = __builtin_amdgcn_cvt_pk_f32_fp8((int)u[j], false);
            floatx2 hi = __builtin_amdgcn_cvt_pk_f32_fp8((int)u[j], true);
            xlv[j * 2 + 0] = lo;
            xlv[j * 2 + 1] = hi;
            floatx2 s0v = lo + xrv[j * 2 + 0];
            floatx2 s1v = hi + xrv[j * 2 + 1];
            floatx2 g0 = __builtin_elementwise_max(s0v, 0.2f * s0v);
            floatx2 g1 = __builtin_elementwise_max(s1v, 0.2f * s1v);
            p2 += attv[j * 2 + 0] * g0;
            p2 += attv[j * 2 + 1] * g1;
        }
        float p = p2.x + p2.y;
        p += __shfl_xor(p, 1, 64);
        p += __shfl_xor(p, 2, 64);
        p += __shfl_xor(p, 4, 64);
        p += __shfl_xor(p, 8, 64);
        float ex = act ? expf(p) : 0.f;
        den += ex;
        floatx2 ex2 = (floatx2){ex, ex};
#pragma unroll
        for (int i = 0; i < NJ * 2; i++) acc[i] += ex2 * xlv[i];
        // ---- rotate ----
#pragma unroll
        for (int j = 0; j < NJ; j++) u[j] = un[j];
    }

    // cross-quad butterfly (scalar view of packed acc)
    float* af = (float*)acc;
#pragma unroll
    for (int o = 16; o <= 32; o <<= 1) {
        den += __shfl_xor(den, o, 64);
#pragma unroll
        for (int i = 0; i < NJ * 4; i++) af[i] += __shfl_xor(af[i], o, 64);
    }

    if (half == 1 && lane < 16) {
        if (lane == 0) sden[pairIdx] = den;
#pragma unroll
        for (int j = 0; j < NJ; j++)
            *(float4*)(&sacc[pairIdx][sl * 4 + j * 64]) =
                make_float4(af[j * 4 + 0], af[j * 4 + 1], af[j * 4 + 2], af[j * 4 + 3]);
    }
    __syncthreads();
    if (half == 0 && lane < 16) {
        den += sden[pairIdx];
        const float inv = 1.f / (den + 1e-16f);
#pragma unroll
        for (int j = 0; j < NJ; j++) {
            const int f0 = sl * 4 + j * 64;
            if (f0 >= SOUT) continue;
            float4 o4 = *(float4*)(&sacc[pairIdx][f0]);
            float vv[4] = {af[j * 4 + 0] + o4.x, af[j * 4 + 1] + o4.y,
                           af[j * 4 + 2] + o4.z, af[j * 4 + 3] + o4.w};
            float r[4];
#pragma unroll
            for (int cc = 0; cc < 4; cc++) {
                const int f = f0 + cc;
                float v = 0.f;
                if (f < F) v = fmaxf(vv[cc] * inv + bias[f], 0.f);
                r[cc] = v;
            }
            if constexpr (sizeof(TOUT) == 4) {   // float out (regular stores)
                *(float4*)((float*)out + (size_t)wid * SOUT + f0) =
                    make_float4(r[0], r[1], r[2], r[3]);
            } else {                             // bf16 out (regular stores)
                unsigned* op = (unsigned*)out + (size_t)wid * (SOUT / 2) + (f0 >> 1);
                op[0] = pk2bf(r[0], r[1]);
                op[1] = pk2bf(r[2], r[3]);
            }
        }
    }
}

// ---------------------------------------------------------------------------
// Layer-3 projections: xl3 = xo @ Wl3, xr3 = xo @ Wr3   (K=100)
// ---------------------------------------------------------------------------
__global__ __launch_bounds__(256) void gemm_vec1_kernel(
    const float* __restrict__ xo, const float* __restrict__ wl,
    const float* __restrict__ wr, float* __restrict__ xl3,
    float* __restrict__ xr3, int M, int ldx) {
    const int wid = blockIdx.x * 4 + (threadIdx.x >> 6);
    const int lane = threadIdx.x & 63;
    if (wid >= M) return;
    float a = 0.f, b = 0.f;
    for (int f = lane; f < 100; f += 64) {
        float v = xo[(size_t)wid * ldx + f];
        a += v * wl[f];
        b += v * wr[f];
    }
    a = wave_reduce_sum(a);
    b = wave_reduce_sum(b);
    if (lane == 0) { xl3[wid] = a; xr3[wid] = b; }
}

// ---------------------------------------------------------------------------
// Layer-3 GAT (F=1): wave per node, lanes parallel over edges.
// ---------------------------------------------------------------------------
__global__ __launch_bounds__(256) void gat3_kernel(
    const float* __restrict__ xl3, const float* __restrict__ xr3,
    const float* __restrict__ att3, const float* __restrict__ b3,
    const int* __restrict__ off, const int* __restrict__ ssrc,
    float* __restrict__ out, int n) {
    const int wid = blockIdx.x * 4 + (threadIdx.x >> 6);
    const int lane = threadIdx.x & 63;
    if (wid >= n) return;
    const float xrv = xr3[wid];
    const float att = att3[0];
    float num = 0.f, den = 0.f;
    const int s0 = off[wid], s1 = off[wid + 1];
    for (int e = s0 - 1 + lane; e < s1; e += 64) {
        int src = (e < s0) ? wid : ssrc[e];
        float xlv = xl3[src];
        float t = xlv + xrv;
        float g = t > 0.f ? t : 0.2f * t;
        float ex = expf(g * att);
        den += ex;
        num += ex * xlv;
    }
    num = wave_reduce_sum(num);
    den = wave_reduce_sum(den);
    if (lane == 0) out[wid] = num / (den + 1e-16f) + b3[0];
}

// ---------------------------------------------------------------------------
// Link-prediction loss on fp8 z [N,128]. Per-block partials (no same-address
// atomics — they serialized cross-XCD at ~15 ns each, R8 evidence).
// ---------------------------------------------------------------------------
__global__ __launch_bounds__(256) void loss_kernel(
    const unsigned char* __restrict__ z8, const int* __restrict__ pos,
    const int* __restrict__ neg, float* __restrict__ part, int nb, int E) {
    const int lane = threadIdx.x & 63;
    const int sl = lane & 15;
    const int wlocal = threadIdx.x >> 6;
    const int q = lane >> 4;
    const int nq = gridDim.x * 16;
    const int qid = (blockIdx.x * 4 + wlocal) * 4 + q;
    const int total = 2 * E;
    float psum = 0.f, nsum = 0.f;

    for (int base = qid; base < total; base += 4 * nq) {
        uint2 au[4], bu[4];
        bool act[4], isN[4];
#pragma unroll
        for (int s = 0; s < 4; s++) {
            int it = base + s * nq;
            act[s] = it < total;
            int itc = act[s] ? it : 0;
            isN[s] = itc >= E;
            int e = isN[s] ? itc - E : itc;
            const int* ei = isN[s] ? neg : pos;
            int u = ei[e], v = ei[E + e];
            au[s] = *(const uint2*)(z8 + (size_t)u * 128 + sl * 8);
            bu[s] = *(const uint2*)(z8 + (size_t)v * 128 + sl * 8);
        }
#pragma unroll
        for (int s = 0; s < 4; s++) {
            floatx2 a0 = __builtin_amdgcn_cvt_pk_f32_fp8((int)au[s].x, false);
            floatx2 a1 = __builtin_amdgcn_cvt_pk_f32_fp8((int)au[s].x, true);
            floatx2 a2 = __builtin_amdgcn_cvt_pk_f32_fp8((int)au[s].y, false);
            floatx2 a3 = __builtin_amdgcn_cvt_pk_f32_fp8((int)au[s].y, true);
            floatx2 b0 = __builtin_amdgcn_cvt_pk_f32_fp8((int)bu[s].x, false);
            floatx2 b1 = __builtin_amdgcn_cvt_pk_f32_fp8((int)bu[s].x, true);
            floatx2 b2 = __builtin_amdgcn_cvt_pk_f32_fp8((int)bu[s].y, false);
            floatx2 b3 = __builtin_amdgcn_cvt_pk_f32_fp8((int)bu[s].y, true);
            float p = a0.x * b0.x + a0.y * b0.y + a1.x * b1.x + a1.y * b1.y
                    + a2.x * b2.x + a2.y * b2.y + a3.x * b3.x + a3.y * b3.y;
            p += __shfl_xor(p, 1, 64);
            p += __shfl_xor(p, 2, 64);
            p += __shfl_xor(p, 4, 64);
            p += __shfl_xor(p, 8, 64);
            if (sl == 0 && act[s]) {
                float sig = 1.f / (1.f + expf(-p));
                if (isN[s]) nsum += logf(1.f - sig + 1e-15f);
                else        psum += logf(sig + 1e-15f);
            }
        }
    }
    float pw = wave_reduce_sum(psum);
    float nw = wave_reduce_sum(nsum);
    __shared__ float sp[4], sn[4];
    if (lane == 0) { sp[wlocal] = pw; sn[wlocal] = nw; }
    __syncthreads();
    if (threadIdx.x == 0) {
        part[blockIdx.x]      = sp[0] + sp[1] + sp[2] + sp[3];
        part[nb + blockIdx.x] = sn[0] + sn[1] + sn[2] + sn[3];
    }
}

// Final reduction of per-block partials + scalar outputs.
__global__ __launch_bounds__(1024) void finalize_kernel(
    const float* __restrict__ part, int nb,
    const float* __restrict__ c1, const float* __restrict__ c2,
    float* __restrict__ out, int n, int E) {
    __shared__ float sp[16], sn[16];
    const int tid = threadIdx.x, lane = tid & 63, w = tid >> 6;
    float p = 0.f, q = 0.f;
    for (int i = tid; i < nb; i += 1024) { p += part[i]; q += part[nb + i]; }
    p = wave_reduce_sum(p);
    q = wave_reduce_sum(q);
    if (lane == 0) { sp[w] = p; sn[w] = q; }
    __syncthreads();
    if (tid == 0) {
        float tp = 0.f, tq = 0.f;
#pragma unroll
        for (int i = 0; i < 16; i++) { tp += sp[i]; tq += sn[i]; }
        out[n]     = -(tp + tq) / (float)E;
        out[n + 1] = c1[0];
        out[n + 2] = c2[0];
    }
}

// ---------------------------------------------------------------------------
extern "C" void kernel_launch(void* const* d_in, const int* in_sizes, int n_in,
                              void* d_out, int out_size, void* d_ws, size_t ws_size,
                              hipStream_t stream) {
    const float* x      = (const float*)d_in[0];
    const int*   ei     = (const int*)d_in[1];
    const int*   nei    = (const int*)d_in[2];
    const float* Wl1    = (const float*)d_in[3];
    const float* Wr1    = (const float*)d_in[4];
    const float* att1   = (const float*)d_in[5];
    const float* b1     = (const float*)d_in[6];
    const float* Wl2    = (const float*)d_in[7];
    const float* Wr2    = (const float*)d_in[8];
    const float* att2   = (const float*)d_in[9];
    const float* b2     = (const float*)d_in[10];
    const float* Wl3    = (const float*)d_in[11];
    const float* Wr3    = (const float*)d_in[12];
    const float* att3   = (const float*)d_in[13];
    const float* b3     = (const float*)d_in[14];
    const float* Wlin1  = (const float*)d_in[15];
    const float* blin1  = (const float*)d_in[16];
    const float* Wlin2  = (const float*)d_in[17];
    const float* blin2  = (const float*)d_in[18];
    const float* c1     = (const float*)d_in[19];
    const float* c2     = (const float*)d_in[20];
    float* out = (float*)d_out;

    const int E = in_sizes[1] / 2;   // 504378
    const int N = NODES;
    const int LOSS_BLOCKS = 4096;

    // ---- workspace carve (bytes), ~39 MB, live windows disjoint ----
    char* ws = (char*)d_ws;
    unsigned char*  xl8  = (unsigned char*)(ws + 0);          // [N,304] fp8 (4.14MB < 4MiB L2)
    unsigned char*  xl28 = (unsigned char*)(ws + 0);          // [N,112] fp8 (after gat1)
    __hip_bfloat16* xrb  = (__hip_bfloat16*)(ws + 4194304);   // [N,320] bf16 (L1)
    __hip_bfloat16* xr2b = (__hip_bfloat16*)(ws + 4194304);   // [N,128] bf16 (after gat1)
    float*          xo   = (float*)(ws + 4194304);            // [N,100] f32 (after gat2)
    unsigned char*  z8   = (unsigned char*)(ws + 9645312);    // [N,128] fp8
    __hip_bfloat16* h1b  = (__hip_bfloat16*)(ws + 12915712);  // [N,320] bf16 (gat1 -> L2 GEMM)
    float*          h2   = (float*)(ws + 12915712);           // [N,100] f32 (after L2 GEMM)
    __hip_bfloat16* xb   = (__hip_bfloat16*)(ws + 21637120);  // [N,512] bf16
    __hip_bfloat16* W1T  = (__hip_bfloat16*)(ws + 35591168);  // [640,512]
    __hip_bfloat16* W2T  = (__hip_bfloat16*)(ws + 36246528);  // [256,320]
    __hip_bfloat16* WsT  = (__hip_bfloat16*)(ws + 36410368);  // [256,512]
    float*          bcat = (float*)(ws + 36672512);           // [256]
    float*          xl3  = (float*)(ws + 36673536);
    float*          xr3  = (float*)(ws + 36728064);
    int*            ioff = (int*)(ws + 36782592);             // N+1
    int*            cur  = (int*)(ws + 36837376);             // N
    int*            ssrc = (int*)(ws + 36892160);             // E
    float*          part = (float*)(ws + 38909952);           // [2*LOSS_BLOCKS]

    hipMemsetAsync(cur, 0, sizeof(int) * N, stream);

    // ---- CSR build ----
    hist_kernel<<<(E + 255) / 256, 256, 0, stream>>>(ei + E, cur, E);
    scan_kernel<<<1, 1024, 0, stream>>>(cur, ioff, N);
    scatter_kernel<<<(E + 255) / 256, 256, 0, stream>>>(ei, ei + E, cur, ssrc, E);

    // ---- pack inputs/weights (one fused launch) ----
    convert_all_kernel<<<(540928 + N * 128 + 255) / 256, 256, 0, stream>>>(
        x, Wl1, Wr1, Wl2, Wr2, Wlin1, Wlin2, blin1, blin2,
        W1T, W2T, WsT, bcat, xb, N);

    // ---- layer 1: GEMM -> xl8 fp8 [N,304] + xrb bf16 [N,320] ----
    mfma_gemm<1, __hip_bfloat16><<<dim3(10, 107), 256, 0, stream>>>(
        xb, W1T, (__hip_bfloat16*)nullptr, nullptr, nullptr, xl8, xrb, N, 512, 640, 0);
    gat_f8_kernel<300, 5, 304, 320, 320, 11, __hip_bfloat16>
        <<<(N + 1) / 2, 256, 0, stream>>>(xl8, xrb, att1, b1, ioff, ssrc, h1b, N);

    // ---- layer 2: GEMM -> xl28 fp8 [N,112] + xr2b bf16 [N,128] ----
    mfma_gemm<2, __hip_bfloat16><<<dim3(4, 107), 256, 0, stream>>>(
        h1b, W2T, (__hip_bfloat16*)nullptr, nullptr, nullptr, xl28, xr2b, N, 320, 256, 0);
    gat_f8_kernel<100, 2, 112, 128, 100, 9, float>
        <<<(N + 1) / 2, 256, 0, stream>>>(xl28, xr2b, att2, b2, ioff, ssrc, h2, N);

    // ---- skip connections: xo f32 [N,100], z8 fp8 [N,128] ----
    mfma_gemm<3, float><<<dim3(4, 107), 256, 0, stream>>>(
        xb, WsT, xo, bcat, h2, z8, nullptr, N, 512, 256, 0);

    // ---- reconstruction loss (per-block partials, no atomics) ----
    loss_kernel<<<LOSS_BLOCKS, 256, 0, stream>>>(z8, ei, nei, part, LOSS_BLOCKS, E);

    // ---- layer 3 ----
    gemm_vec1_kernel<<<(N + 3) / 4, 256, 0, stream>>>(xo, Wl3, Wr3, xl3, xr3, N, 100);
    gat3_kernel<<<(N + 3) / 4, 256, 0, stream>>>(xl3, xr3, att3, b3, ioff, ssrc, out, N);

    finalize_kernel<<<1, 1024, 0, stream>>>(part, LOSS_BLOCKS, c1, c2, out, N, E);
}